// Round 5
// baseline (719.657 us; speedup 1.0000x reference)
//
#include <hip/hip_runtime.h>

// GQA group-attention: q/k/v GEMMs (bf16 MFMA) + per-token 16x16 group attention.
// R4': identical to R4 (bench infra failed twice; no kernel signal — same
//     signature as R2, which passed unchanged on resubmit).
//     GEMM ported to the m201-style 8-phase schedule (T3+T4+T5 on T2):
//     BK=64, 2 LDS buffers (128 KB), 4 phases per K-tile (one C-quadrant x K=64,
//     16 MFMA each), per-phase {ds_read frags || 2 stage gload_lds -> s_barrier ->
//     lgkmcnt(0) -> sched_barrier -> setprio(1) MFMA setprio(0) -> s_barrier},
//     single vmcnt(0) per K-tile at phase 3 (loads issued >=1 phase earlier).
//     LDS swizzle re-derived for 128B rows: chunk' = chunk ^ (row&7), applied as
//     pre-swizzled global SOURCE + swizzled read (rule #21). attn/cvt unchanged.

#define DIM 2048
#define NTOT 6144   // 3*DIM, concatenated q|k|v per token
#define DG 128      // per-group dim
#define NG 16       // groups
#define BK 64
#define KT64 (DIM / BK)     // 32 K-tiles

typedef __bf16 bf16x8 __attribute__((ext_vector_type(8)));
typedef float f32x4 __attribute__((ext_vector_type(4)));
typedef unsigned short u16;
typedef unsigned int u32;

__device__ __forceinline__ u16 f2bf(float f) {
  u32 u = __float_as_uint(f);
  u = (u + 0x7fffu + ((u >> 16) & 1u)) >> 16;  // RNE
  return (u16)u;
}

__device__ __forceinline__ void gload16(const __bf16* g, __bf16* l) {
  // async global->LDS DMA, 16B per lane; LDS dest = wave-uniform base + lane*16,
  // global src is per-lane.
  __builtin_amdgcn_global_load_lds(
      (__attribute__((address_space(1))) void*)(void*)g,
      (__attribute__((address_space(3))) void*)l, 16, 0, 0);
}

__global__ __launch_bounds__(256) void cvt_kernel(const float* __restrict__ src,
                                                  u16* __restrict__ dst, int n4) {
  int i = blockIdx.x * 256 + threadIdx.x;
  if (i >= n4) return;
  float4 f = ((const float4*)src)[i];
  ushort4 o;
  o.x = f2bf(f.x); o.y = f2bf(f.y); o.z = f2bf(f.z); o.w = f2bf(f.w);
  ((ushort4*)dst)[i] = o;
}

__global__ __launch_bounds__(256) void cvtW_kernel(const float* __restrict__ wq,
                                                   const float* __restrict__ wk,
                                                   const float* __restrict__ wv,
                                                   u16* __restrict__ dst, int n4each) {
  int m = blockIdx.y;
  const float* s = (m == 0) ? wq : (m == 1) ? wk : wv;
  int i = blockIdx.x * 256 + threadIdx.x;
  if (i >= n4each) return;
  float4 f = ((const float4*)s)[i];
  ushort4 o;
  o.x = f2bf(f.x); o.y = f2bf(f.y); o.z = f2bf(f.z); o.w = f2bf(f.w);
  ((ushort4*)dst)[(size_t)m * n4each + i] = o;
}

// C[row][col] = A[row][:] . W[col][:] + bias, stored bf16.
// 256x256 tile, 8 waves (2x4), per-wave 128x64 output (acc[8][4]).
// LDS: 2 buffers x (A[256][64] + B[256][64]) bf16 = 2 x 64 KB = 128 KB.
// Within a row (128 B = 8 chunks of 16 B): LDS chunk c holds global chunk
// c ^ (row & 7)  (involution; conflict-free quarter-wave column reads).
__global__ __launch_bounds__(512, 1) void gemm_qkv(const __bf16* __restrict__ A,
                                                   const __bf16* __restrict__ W,
                                                   const float* __restrict__ bq,
                                                   const float* __restrict__ bk,
                                                   const float* __restrict__ bv,
                                                   u16* __restrict__ C) {
  __shared__ __bf16 lds[2 * 32768];  // elements; buf b at b*32768, A then B(+16384)

  const int tid = threadIdx.x;       // 0..511
  const int lane = tid & 63;
  const int w = tid >> 6;            // wave 0..7
  const int wm = w >> 2, wn = w & 3; // 2 x 4 wave grid
  const int lm = lane & 15, kq = lane >> 4;

  // XCD-bijective swizzle: nwg = 1536 = 8 * 192.
  const int bid = blockIdx.x;
  const int swz = (bid & 7) * 192 + (bid >> 3);
  const int bm = swz % 64;           // M tile 0..63
  const int bn = swz / 64;           // N tile 0..23 (consecutive ids share B panel)

  // Staging: half-tile = 128 rows x 64 cols x 2B = 16 KB = 2 gload16 x 512 thr.
  // chunk c = i*512 + tid -> row_local = c>>3, chunk-in-row = c&7;
  // pre-swizzled SOURCE chunk = (c&7) ^ ((c>>3)&7) = (tid&7) ^ ((tid>>3)&7).
  const int srow = tid >> 3;                                // 0..63
  const int scol = ((tid & 7) ^ ((tid >> 3) & 7)) * 8;      // elements
  const __bf16* pA = A + (size_t)(bm * 256 + srow) * DIM + scol;
  const __bf16* pB = W + (size_t)(bn * 256 + srow) * DIM + scol;

  // STAGEH(tile, p): half-tile p of tile 'tt' -> buf[tt&1].
  // p: 0=A rows 0..127, 1=A rows 128..255, 2=B rows 0..127, 3=B rows 128..255.
#define STAGEH(tt, p)                                                         \
  {                                                                           \
    __bf16* db = lds + ((tt) & 1) * 32768 + ((p) >> 1) * 16384 +              \
                 ((p) & 1) * 8192 + tid * 8;                                  \
    const __bf16* sp = (((p) >> 1) == 0 ? pA : pB) +                          \
                       (size_t)(((p) & 1) * 128) * DIM + (size_t)(tt) * BK;   \
    gload16(sp, db);                                                          \
    gload16(sp + (size_t)64 * DIM, db + 4096);                                \
  }

  f32x4 acc[8][4];
#pragma unroll
  for (int i = 0; i < 8; ++i)
#pragma unroll
    for (int j = 0; j < 4; ++j) acc[i][j] = (f32x4){0.f, 0.f, 0.f, 0.f};

  // Fragment read offsets (elements), swizzled: global chunk gc = kk*4 + kq at
  // row r reads LDS chunk gc ^ (r&7); r&7 == lm&7 (other row terms are x8/x16).
  int aoff[2][2], boff[2][2];
#pragma unroll
  for (int ih = 0; ih < 2; ++ih)
#pragma unroll
    for (int kk = 0; kk < 2; ++kk)
      aoff[ih][kk] = (wm * 128 + ih * 64 + lm) * 64 + (((kk << 2) | kq) ^ (lm & 7)) * 8;
#pragma unroll
  for (int jh = 0; jh < 2; ++jh)
#pragma unroll
    for (int kk = 0; kk < 2; ++kk)
      boff[jh][kk] = (wn * 64 + jh * 32 + lm) * 64 + (((kk << 2) | kq) ^ (lm & 7)) * 8;

  bf16x8 af[4][2], bfr[2][2];

  // Phase (ih, jh): C-quadrant i in [ih*4,ih*4+4), j in [jh*2,jh*2+2), K=64.
  // A-frags read at jh==0, reused at jh==1. Stage half-tile p of tile tv+1.
#define PH(tv, ih, jh, dostage, p)                                            \
  {                                                                           \
    const __bf16* bufb = lds + ((tv) & 1) * 32768;                            \
    if ((jh) == 0) {                                                          \
      _Pragma("unroll") for (int ir = 0; ir < 4; ++ir)                        \
        _Pragma("unroll") for (int kk = 0; kk < 2; ++kk)                      \
          af[ir][kk] = *(const bf16x8*)(bufb + aoff[ih][kk] + ir * 1024);     \
    }                                                                         \
    _Pragma("unroll") for (int jr = 0; jr < 2; ++jr)                          \
      _Pragma("unroll") for (int kk = 0; kk < 2; ++kk)                        \
        bfr[jr][kk] = *(const bf16x8*)(bufb + 16384 + boff[jh][kk] + jr * 1024); \
    if (dostage) STAGEH((tv) + 1, p);                                         \
    __builtin_amdgcn_sched_barrier(0);                                       \
    asm volatile("s_barrier" ::: "memory");                                   \
    asm volatile("s_waitcnt lgkmcnt(0)" ::: "memory");                        \
    __builtin_amdgcn_sched_barrier(0);                                       \
    __builtin_amdgcn_s_setprio(1);                                            \
    _Pragma("unroll") for (int ir = 0; ir < 4; ++ir)                          \
      _Pragma("unroll") for (int jr = 0; jr < 2; ++jr)                        \
        _Pragma("unroll") for (int kk = 0; kk < 2; ++kk)                      \
          acc[(ih) * 4 + ir][(jh) * 2 + jr] =                                 \
              __builtin_amdgcn_mfma_f32_16x16x32_bf16(                        \
                  af[ir][kk], bfr[jr][kk], acc[(ih) * 4 + ir][(jh) * 2 + jr], \
                  0, 0, 0);                                                   \
    __builtin_amdgcn_s_setprio(0);                                            \
    if ((p) == 3) asm volatile("s_waitcnt vmcnt(0)" ::: "memory");            \
    asm volatile("s_barrier" ::: "memory");                                   \
  }

  // prologue: stage tile 0 fully, certify residency for all waves
  STAGEH(0, 0) STAGEH(0, 1) STAGEH(0, 2) STAGEH(0, 3)
  asm volatile("s_waitcnt vmcnt(0)" ::: "memory");
  asm volatile("s_barrier" ::: "memory");

#pragma unroll 1
  for (int t = 0; t < KT64 - 1; ++t) {
    PH(t, 0, 0, 1, 0)
    PH(t, 0, 1, 1, 1)
    PH(t, 1, 0, 1, 2)
    PH(t, 1, 1, 1, 3)
  }
  // last tile: no staging
  PH(KT64 - 1, 0, 0, 0, 0)
  PH(KT64 - 1, 0, 1, 0, 1)
  PH(KT64 - 1, 1, 0, 0, 2)
  PH(KT64 - 1, 1, 1, 0, 3)
#undef PH
#undef STAGEH

  // epilogue: C/D layout col=lane&15, row=(lane>>4)*4+reg (verified m89/m91)
  const int mat = bn >> 3;  // 8 N-tiles per matrix (2048/256)
  const float* bias = (mat == 0) ? bq : (mat == 1) ? bk : bv;
  const int colb = bn * 256 + wn * 64 + lm;
  const int rowb = bm * 256 + wm * 128 + kq * 4;
#pragma unroll
  for (int i = 0; i < 8; ++i) {
#pragma unroll
    for (int j = 0; j < 4; ++j) {
      const int col = colb + j * 16;
      const float bs = bias[col & (DIM - 1)];
#pragma unroll
      for (int r = 0; r < 4; ++r) {
        const int row = rowb + i * 16 + r;
        C[(size_t)row * NTOT + col] = f2bf(acc[i][j][r] + bs);
      }
    }
  }
}

__device__ __forceinline__ void unpack8(uint4 v, float* f) {
  f[0] = __uint_as_float(v.x << 16);
  f[1] = __uint_as_float(v.x & 0xffff0000u);
  f[2] = __uint_as_float(v.y << 16);
  f[3] = __uint_as_float(v.y & 0xffff0000u);
  f[4] = __uint_as_float(v.z << 16);
  f[5] = __uint_as_float(v.z & 0xffff0000u);
  f[6] = __uint_as_float(v.w << 16);
  f[7] = __uint_as_float(v.w & 0xffff0000u);
}

// One WAVE per token. Lane = s*16+g: group g (0..15), dim-quarter s (0..3, 32 dims).
// K|V (8KB contiguous) staged into a private LDS region via global_load_lds;
// no cross-wave sharing -> no barriers, just own-wave vmcnt(0).
__global__ __launch_bounds__(256) void attn_kernel(const u16* __restrict__ qkv,
                                                   float* __restrict__ out) {
  __shared__ __bf16 kv[4][4096];  // per-wave 8KB: k[16][128] then v[16][128]

  const int tid = threadIdx.x;
  const int lane = tid & 63;
  const int w = tid >> 6;
  const int token = blockIdx.x * 4 + w;
  const int g = lane & 15, s = lane >> 4;

  const __bf16* base = (const __bf16*)(qkv) + (size_t)token * NTOT;

  // stage k|v: 8 instrs x (64 lanes x 16B) = 8KB, fully coalesced
  const __bf16* kvsrc = base + DIM;
#pragma unroll
  for (int i = 0; i < 8; ++i)
    gload16(kvsrc + i * 512 + lane * 8, (__bf16*)kv[w] + i * 512);

  // q fragment for (g, s): 32 dims -> registers (overlaps with K/V staging)
  float qf[32];
  const __bf16* qsrc = base + g * DG + s * 32;
#pragma unroll
  for (int j = 0; j < 4; ++j) {
    uint4 qc = *(const uint4*)(qsrc + j * 8);
    unpack8(qc, qf + j * 8);
  }

  asm volatile("s_waitcnt vmcnt(0)" ::: "memory");  // own stages done; region private

  // scores: sc[h] = q[g]:32dims . k[h]:32dims, then 4-lane reduce over s
  float sc[16];
  const __bf16* kl = (const __bf16*)kv[w] + s * 32;
#pragma unroll 4
  for (int h = 0; h < 16; ++h) {
    const uint4* kr = (const uint4*)(kl + h * DG);
    float a = 0.f;
#pragma unroll
    for (int j = 0; j < 4; ++j) {
      float kf[8];
      unpack8(kr[j], kf);
#pragma unroll
      for (int e = 0; e < 8; ++e) a = fmaf(qf[j * 8 + e], kf[e], a);
    }
    sc[h] = a;
  }
#pragma unroll
  for (int h = 0; h < 16; ++h) {
    float v = sc[h];
    v += __shfl_xor(v, 16);
    v += __shfl_xor(v, 32);
    sc[h] = v;  // all 4 s-lanes now hold the full dot
  }

  const float scale = 0.08838834764831845f;  // 1/sqrt(128)
  float mx = sc[0] * scale;
#pragma unroll
  for (int h = 1; h < 16; ++h) mx = fmaxf(mx, sc[h] * scale);
  float p[16], sum = 0.f;
#pragma unroll
  for (int h = 0; h < 16; ++h) {
    p[h] = __expf(sc[h] * scale - mx);
    sum += p[h];
  }
  const float inv = 1.f / sum;
#pragma unroll
  for (int h = 0; h < 16; ++h) p[h] *= inv;

  // out[g][s*32 .. +32] = sum_h p[h] * v[h][dims]
  float o[32];
#pragma unroll
  for (int e = 0; e < 32; ++e) o[e] = 0.f;
  const __bf16* vl = (const __bf16*)kv[w] + 2048 + s * 32;
#pragma unroll 4
  for (int h = 0; h < 16; ++h) {
    const uint4* vr = (const uint4*)(vl + h * DG);
    const float ph = p[h];
#pragma unroll
    for (int j = 0; j < 4; ++j) {
      float vf[8];
      unpack8(vr[j], vf);
#pragma unroll
      for (int e = 0; e < 8; ++e) o[j * 8 + e] = fmaf(ph, vf[e], o[j * 8 + e]);
    }
  }

  float* ob = out + (size_t)token * DIM + g * DG + s * 32;
#pragma unroll
  for (int j = 0; j < 8; ++j) {
    float4 v4 = {o[j * 4], o[j * 4 + 1], o[j * 4 + 2], o[j * 4 + 3]};
    ((float4*)ob)[j] = v4;
  }
}

extern "C" void kernel_launch(void* const* d_in, const int* in_sizes, int n_in,
                              void* d_out, int out_size, void* d_ws, size_t ws_size,
                              hipStream_t stream) {
  const float* x  = (const float*)d_in[0];
  const float* Wq = (const float*)d_in[1];
  const float* bq = (const float*)d_in[2];
  const float* Wk = (const float*)d_in[3];
  const float* bk = (const float*)d_in[4];
  const float* Wv = (const float*)d_in[5];
  const float* bv = (const float*)d_in[6];
  float* out = (float*)d_out;

  const int M = in_sizes[0] / DIM;  // 16384 tokens

  // ws layout: x_bf16 [M*2048] | W_bf16 [3*2048*2048] | qkv_bf16 [M*6144]
  u16* xb  = (u16*)d_ws;
  u16* wb  = xb + (size_t)M * DIM;
  u16* qkv = wb + (size_t)3 * DIM * DIM;

  const int n4x = (M * DIM) / 4;
  cvt_kernel<<<dim3((n4x + 255) / 256), 256, 0, stream>>>(x, xb, n4x);
  const int n4w = (DIM * DIM) / 4;
  cvtW_kernel<<<dim3((n4w + 255) / 256, 3), 256, 0, stream>>>(Wq, Wk, Wv, wb, n4w);

  gemm_qkv<<<dim3((M / 256) * (NTOT / 256)), 512, 0, stream>>>(
      (const __bf16*)xb, (const __bf16*)wb, bq, bk, bv, qkv);

  attn_kernel<<<dim3(M / 4), 256, 0, stream>>>(qkv, out);
}

// Round 6
// 713.863 us; speedup vs baseline: 1.0081x; 1.0081x over previous
//
#include <hip/hip_runtime.h>

// GQA group-attention: q/k/v GEMMs (bf16 MFMA) + per-token 16x16 group attention.
// R5: GEMM k-split-half phases + COUNTED vmcnt (the real T4). BK=64, 2 dbuf
//     (128 KB), LDS halves split along K (A-k0|B-k0|A-k1|B-k1, 16 KB each).
//     Phases (kk, i-half): ph0/1 compute kk=0, ph2/3 kk=1. Stage one half of
//     tile t+1 per phase (A-k0@ph0, B-k0@ph1, A-k1@ph2, B-k1@ph3) -> every
//     half has 2-4 phases of lead. vmcnt(4) at ends of ph1/ph3 only; never 0
//     in main loop (m218: counted-vs-drain0 = +38-73%). Swizzle = R3's
//     HW-verified 64B-row pattern (slot ^ ((row>>1)&3), both sides).
//     attn/cvt unchanged.

#define DIM 2048
#define NTOT 6144   // 3*DIM, concatenated q|k|v per token
#define DG 128      // per-group dim
#define NG 16       // groups
#define BK 64
#define KT64 (DIM / BK)     // 32 K-tiles

typedef __bf16 bf16x8 __attribute__((ext_vector_type(8)));
typedef float f32x4 __attribute__((ext_vector_type(4)));
typedef unsigned short u16;
typedef unsigned int u32;

__device__ __forceinline__ u16 f2bf(float f) {
  u32 u = __float_as_uint(f);
  u = (u + 0x7fffu + ((u >> 16) & 1u)) >> 16;  // RNE
  return (u16)u;
}

__device__ __forceinline__ void gload16(const __bf16* g, __bf16* l) {
  // async global->LDS DMA, 16B per lane; LDS dest = wave-uniform base + lane*16,
  // global src is per-lane.
  __builtin_amdgcn_global_load_lds(
      (__attribute__((address_space(1))) void*)(void*)g,
      (__attribute__((address_space(3))) void*)l, 16, 0, 0);
}

__global__ __launch_bounds__(256) void cvt_kernel(const float* __restrict__ src,
                                                  u16* __restrict__ dst, int n4) {
  int i = blockIdx.x * 256 + threadIdx.x;
  if (i >= n4) return;
  float4 f = ((const float4*)src)[i];
  ushort4 o;
  o.x = f2bf(f.x); o.y = f2bf(f.y); o.z = f2bf(f.z); o.w = f2bf(f.w);
  ((ushort4*)dst)[i] = o;
}

__global__ __launch_bounds__(256) void cvtW_kernel(const float* __restrict__ wq,
                                                   const float* __restrict__ wk,
                                                   const float* __restrict__ wv,
                                                   u16* __restrict__ dst, int n4each) {
  int m = blockIdx.y;
  const float* s = (m == 0) ? wq : (m == 1) ? wk : wv;
  int i = blockIdx.x * 256 + threadIdx.x;
  if (i >= n4each) return;
  float4 f = ((const float4*)s)[i];
  ushort4 o;
  o.x = f2bf(f.x); o.y = f2bf(f.y); o.z = f2bf(f.z); o.w = f2bf(f.w);
  ((ushort4*)dst)[(size_t)m * n4each + i] = o;
}

// C[row][col] = A[row][:] . W[col][:] + bias, stored bf16.
// 256x256 tile, 8 waves (2x4), per-wave 128x64 output (acc[8][4]).
// LDS: 2 dbuf x 4 regions x 8192 elem (16 KB): A-k0 | B-k0 | A-k1 | B-k1.
// Region rows = 256, row = 64 B (4 slots of 16 B); LDS slot s of row r holds
// global slot s ^ ((r>>1)&3)  (involution; HW-verified 0-conflict in R3).
__global__ __launch_bounds__(512, 1) void gemm_qkv(const __bf16* __restrict__ A,
                                                   const __bf16* __restrict__ W,
                                                   const float* __restrict__ bq,
                                                   const float* __restrict__ bk,
                                                   const float* __restrict__ bv,
                                                   u16* __restrict__ C) {
  __shared__ __bf16 lds[2 * 32768];  // 128 KB

  const int tid = threadIdx.x;       // 0..511
  const int lane = tid & 63;
  const int w = tid >> 6;            // wave 0..7
  const int wm = w >> 2, wn = w & 3; // 2 x 4 wave grid
  const int lm = lane & 15, kq = lane >> 4;

  // XCD-bijective swizzle: nwg = 1536 = 8 * 192.
  const int bid = blockIdx.x;
  const int swz = (bid & 7) * 192 + (bid >> 3);
  const int bm = swz % 64;           // M tile 0..63
  const int bn = swz / 64;           // N tile 0..23 (consecutive ids share B panel)

  // Staging a 16 KB region (256 rows x 32 k): 2 gload16 x 512 thr.
  // instr0 rows 0..127 (row = tid>>2, slot = tid&3), instr1 rows +128.
  // SOURCE slot pre-swizzled: (tid&3) ^ ((tid>>3)&3)  [(row>>1)&3 == (tid>>3)&3].
  const int scol = ((tid & 3) ^ ((tid >> 3) & 3)) * 8;      // elements
  const __bf16* pA = A + (size_t)(bm * 256 + (tid >> 2)) * DIM + scol;
  const __bf16* pB = W + (size_t)(bn * 256 + (tid >> 2)) * DIM + scol;

  // Stage region (kk, isB) of tile tt into dbuf[tt&1].
#define STAGEH(tt, kk, isB)                                                   \
  {                                                                           \
    __bf16* db = lds + ((tt) & 1) * 32768 + ((kk) * 2 + (isB)) * 8192 +       \
                 tid * 8;                                                     \
    const __bf16* sp = ((isB) ? pB : pA) + (size_t)(tt) * BK + (kk) * 32;     \
    gload16(sp, db);                                                          \
    gload16(sp + (size_t)128 * DIM, db + 4096);                               \
  }

  f32x4 acc[8][4];
#pragma unroll
  for (int i = 0; i < 8; ++i)
#pragma unroll
    for (int j = 0; j < 4; ++j) acc[i][j] = (f32x4){0.f, 0.f, 0.f, 0.f};

  // Fragment read offsets within a region (elements): row r, chunk kq, swizzled
  // chunk = kq ^ ((r>>1)&3) = kq ^ ((lm>>1)&3) (other row terms are x16).
  const int sw = (kq ^ ((lm >> 1) & 3)) * 8;
  const int aoff = (wm * 128 + lm) * 32 + sw;   // + i*512
  const int boff = (wn * 64 + lm) * 32 + sw;    // + j*512

  bf16x8 af[4], bf[4];

  // Phase (kk, ih): MFMA acc[ih*4+ir][jr] over K-half kk (16 MFMA).
  // A frags (ih*4+ir, kk) read every phase (4 reads); B frags (jr, kk) read at
  // ih==0 (4 reads), reused at ih==1. Stage region (kk, ih) of tile tv+1.
  // vmN: -1 = no wait; 4 = vmcnt(4); 0 = vmcnt(0) (epilogue only).
#define PH(tv, kk, ih, dostage, vmN)                                          \
  {                                                                           \
    const __bf16* bufb = lds + ((tv) & 1) * 32768 + (kk) * 16384;             \
    _Pragma("unroll") for (int ir = 0; ir < 4; ++ir)                          \
      af[ir] = *(const bf16x8*)(bufb + aoff + ((ih) * 4 + ir) * 512);         \
    if ((ih) == 0) {                                                          \
      _Pragma("unroll") for (int jr = 0; jr < 4; ++jr)                        \
        bf[jr] = *(const bf16x8*)(bufb + 8192 + boff + jr * 512);             \
    }                                                                         \
    if (dostage) STAGEH((tv) + 1, kk, ih)                                     \
    __builtin_amdgcn_sched_barrier(0);                                        \
    asm volatile("s_barrier" ::: "memory");                                   \
    asm volatile("s_waitcnt lgkmcnt(0)" ::: "memory");                        \
    __builtin_amdgcn_sched_barrier(0);                                        \
    __builtin_amdgcn_s_setprio(1);                                            \
    _Pragma("unroll") for (int ir = 0; ir < 4; ++ir)                          \
      _Pragma("unroll") for (int jr = 0; jr < 4; ++jr)                        \
        acc[(ih) * 4 + ir][jr] = __builtin_amdgcn_mfma_f32_16x16x32_bf16(     \
            af[ir], bf[jr], acc[(ih) * 4 + ir][jr], 0, 0, 0);                 \
    __builtin_amdgcn_s_setprio(0);                                            \
    if ((vmN) == 4) asm volatile("s_waitcnt vmcnt(4)" ::: "memory");          \
    if ((vmN) == 0) asm volatile("s_waitcnt vmcnt(0)" ::: "memory");          \
    asm volatile("s_barrier" ::: "memory");                                   \
  }

  // prologue: stage all 4 regions of tile 0; certify k0 pair, k1 stays in flight
  STAGEH(0, 0, 0) STAGEH(0, 0, 1) STAGEH(0, 1, 0) STAGEH(0, 1, 1)
  asm volatile("s_waitcnt vmcnt(4)" ::: "memory");
  asm volatile("s_barrier" ::: "memory");

#pragma unroll 1
  for (int t = 0; t < KT64 - 1; ++t) {
    PH(t, 0, 0, 1, -1)
    PH(t, 0, 1, 1, 4)    // certifies A-k1(t), B-k1(t) (issued 2-3 phases ago)
    PH(t, 1, 0, 1, -1)
    PH(t, 1, 1, 1, 4)    // certifies A-k0(t+1), B-k0(t+1) (3-4 phases ago)
  }
  // last tile: no staging; drain k1 halves before ph2 reads them
  PH(KT64 - 1, 0, 0, 0, -1)
  PH(KT64 - 1, 0, 1, 0, 0)
  PH(KT64 - 1, 1, 0, 0, -1)
  PH(KT64 - 1, 1, 1, 0, -1)
#undef PH
#undef STAGEH

  // epilogue: C/D layout col=lane&15, row=(lane>>4)*4+reg (verified m89/m91)
  const int mat = bn >> 3;  // 8 N-tiles per matrix (2048/256)
  const float* bias = (mat == 0) ? bq : (mat == 1) ? bk : bv;
  const int colb = bn * 256 + wn * 64 + lm;
  const int rowb = bm * 256 + wm * 128 + kq * 4;
#pragma unroll
  for (int i = 0; i < 8; ++i) {
#pragma unroll
    for (int j = 0; j < 4; ++j) {
      const int col = colb + j * 16;
      const float bs = bias[col & (DIM - 1)];
#pragma unroll
      for (int r = 0; r < 4; ++r) {
        const int row = rowb + i * 16 + r;
        C[(size_t)row * NTOT + col] = f2bf(acc[i][j][r] + bs);
      }
    }
  }
}

__device__ __forceinline__ void unpack8(uint4 v, float* f) {
  f[0] = __uint_as_float(v.x << 16);
  f[1] = __uint_as_float(v.x & 0xffff0000u);
  f[2] = __uint_as_float(v.y << 16);
  f[3] = __uint_as_float(v.y & 0xffff0000u);
  f[4] = __uint_as_float(v.z << 16);
  f[5] = __uint_as_float(v.z & 0xffff0000u);
  f[6] = __uint_as_float(v.w << 16);
  f[7] = __uint_as_float(v.w & 0xffff0000u);
}

// One WAVE per token. Lane = s*16+g: group g (0..15), dim-quarter s (0..3, 32 dims).
// K|V (8KB contiguous) staged into a private LDS region via global_load_lds;
// no cross-wave sharing -> no barriers, just own-wave vmcnt(0).
__global__ __launch_bounds__(256) void attn_kernel(const u16* __restrict__ qkv,
                                                   float* __restrict__ out) {
  __shared__ __bf16 kv[4][4096];  // per-wave 8KB: k[16][128] then v[16][128]

  const int tid = threadIdx.x;
  const int lane = tid & 63;
  const int w = tid >> 6;
  const int token = blockIdx.x * 4 + w;
  const int g = lane & 15, s = lane >> 4;

  const __bf16* base = (const __bf16*)(qkv) + (size_t)token * NTOT;

  // stage k|v: 8 instrs x (64 lanes x 16B) = 8KB, fully coalesced
  const __bf16* kvsrc = base + DIM;
#pragma unroll
  for (int i = 0; i < 8; ++i)
    gload16(kvsrc + i * 512 + lane * 8, (__bf16*)kv[w] + i * 512);

  // q fragment for (g, s): 32 dims -> registers (overlaps with K/V staging)
  float qf[32];
  const __bf16* qsrc = base + g * DG + s * 32;
#pragma unroll
  for (int j = 0; j < 4; ++j) {
    uint4 qc = *(const uint4*)(qsrc + j * 8);
    unpack8(qc, qf + j * 8);
  }

  asm volatile("s_waitcnt vmcnt(0)" ::: "memory");  // own stages done; region private

  // scores: sc[h] = q[g]:32dims . k[h]:32dims, then 4-lane reduce over s
  float sc[16];
  const __bf16* kl = (const __bf16*)kv[w] + s * 32;
#pragma unroll 4
  for (int h = 0; h < 16; ++h) {
    const uint4* kr = (const uint4*)(kl + h * DG);
    float a = 0.f;
#pragma unroll
    for (int j = 0; j < 4; ++j) {
      float kf[8];
      unpack8(kr[j], kf);
#pragma unroll
      for (int e = 0; e < 8; ++e) a = fmaf(qf[j * 8 + e], kf[e], a);
    }
    sc[h] = a;
  }
#pragma unroll
  for (int h = 0; h < 16; ++h) {
    float v = sc[h];
    v += __shfl_xor(v, 16);
    v += __shfl_xor(v, 32);
    sc[h] = v;  // all 4 s-lanes now hold the full dot
  }

  const float scale = 0.08838834764831845f;  // 1/sqrt(128)
  float mx = sc[0] * scale;
#pragma unroll
  for (int h = 1; h < 16; ++h) mx = fmaxf(mx, sc[h] * scale);
  float p[16], sum = 0.f;
#pragma unroll
  for (int h = 0; h < 16; ++h) {
    p[h] = __expf(sc[h] * scale - mx);
    sum += p[h];
  }
  const float inv = 1.f / sum;
#pragma unroll
  for (int h = 0; h < 16; ++h) p[h] *= inv;

  // out[g][s*32 .. +32] = sum_h p[h] * v[h][dims]
  float o[32];
#pragma unroll
  for (int e = 0; e < 32; ++e) o[e] = 0.f;
  const __bf16* vl = (const __bf16*)kv[w] + 2048 + s * 32;
#pragma unroll 4
  for (int h = 0; h < 16; ++h) {
    const uint4* vr = (const uint4*)(vl + h * DG);
    const float ph = p[h];
#pragma unroll
    for (int j = 0; j < 4; ++j) {
      float vf[8];
      unpack8(vr[j], vf);
#pragma unroll
      for (int e = 0; e < 8; ++e) o[j * 8 + e] = fmaf(ph, vf[e], o[j * 8 + e]);
    }
  }

  float* ob = out + (size_t)token * DIM + g * DG + s * 32;
#pragma unroll
  for (int j = 0; j < 8; ++j) {
    float4 v4 = {o[j * 4], o[j * 4 + 1], o[j * 4 + 2], o[j * 4 + 3]};
    ((float4*)ob)[j] = v4;
  }
}

extern "C" void kernel_launch(void* const* d_in, const int* in_sizes, int n_in,
                              void* d_out, int out_size, void* d_ws, size_t ws_size,
                              hipStream_t stream) {
  const float* x  = (const float*)d_in[0];
  const float* Wq = (const float*)d_in[1];
  const float* bq = (const float*)d_in[2];
  const float* Wk = (const float*)d_in[3];
  const float* bk = (const float*)d_in[4];
  const float* Wv = (const float*)d_in[5];
  const float* bv = (const float*)d_in[6];
  float* out = (float*)d_out;

  const int M = in_sizes[0] / DIM;  // 16384 tokens

  // ws layout: x_bf16 [M*2048] | W_bf16 [3*2048*2048] | qkv_bf16 [M*6144]
  u16* xb  = (u16*)d_ws;
  u16* wb  = xb + (size_t)M * DIM;
  u16* qkv = wb + (size_t)3 * DIM * DIM;

  const int n4x = (M * DIM) / 4;
  cvt_kernel<<<dim3((n4x + 255) / 256), 256, 0, stream>>>(x, xb, n4x);
  const int n4w = (DIM * DIM) / 4;
  cvtW_kernel<<<dim3((n4w + 255) / 256, 3), 256, 0, stream>>>(Wq, Wk, Wv, wb, n4w);

  gemm_qkv<<<dim3((M / 256) * (NTOT / 256)), 512, 0, stream>>>(
      (const __bf16*)xb, (const __bf16*)wb, bq, bk, bv, qkv);

  attn_kernel<<<dim3(M / 4), 256, 0, stream>>>(qkv, out);
}